// Round 8
// baseline (2314.627 us; speedup 1.0000x reference)
//
#include <hip/hip_runtime.h>
#include <stdint.h>

// Persistent-kernel RNN: 256 wgs (1/CU), W_hh bf16 resident in LDS (16 j-slices),
// batch split 16 ways; h exchanged via MALL with sc0 sc1 stores + flags (R2
// protocol — best verified; 5 protocol variants all landed 1028-1228 us).
// R10: DIRECT-TO-REGISTER A operand. The staged-LDS structure (global->VGPR->
// LDS->VGPR + ~11 barriers/step) existed only to share the h tile among waves.
// But the MFMA A-fragment layout (lane l15 = row, quad = k-segment) means each
// lane's fragment is ONE contiguous 16B global load: h[(row)][quad*8 + ks*32].
// New decomposition: wave wv owns col-tile jg*64+wv*16, ALL 32 rows, full
// K=1024: per k-step {2 plain global 16B loads (rows r,r+16), 1 LDS B-ld8,
// 2 MFMAs}, fully unrolled so the compiler software-pipelines the 64
// independent loads. Eliminates: LDS staging writes, 256 A ds_reads, the k-pair
// reduction scratch (R8's 7M bank conflicts), and ~8 barriers/step.
// A loads are PLAIN (L1/L2-cacheable): 4-wave read amplification (256KB/CU) is
// deduped by L1 (k-synchronized waves, ~32KB working set); L1 staleness killed
// by per-step buffer_inv sc0 — the R7-VERIFIED coherence combo (R7 passing with
// L1-only inv also proves the XCD L2 never serves stale h after the producers'
// sc0 sc1 write-through). Flags memset per launch closes the latent
// cross-launch stale-flag race (flags previously never re-initialized).
// R9 lesson: data-polling retry storms (27ms outlier) — flags stay.

#define BATCH 512
#define SEQ   256
#define HID   1024
#define CLS   128

#define GB 16          // batch groups
#define GJ 16          // hidden slices
#define BT 32          // batch rows per wg
#define JT 64          // hidden cols per wg
#define KC 256         // head-staging chunk
#define WSTR 1028      // W LDS row stride (halves)
#define SSTR 260       // head stage row stride (halves)
#define HSTR 68        // h-store exchange row stride (halves)
#define SMEM_BYTES ((JT * WSTR + BT * SSTR) * 2)   // 148224 B
#define HBUF_HALVES (BATCH * HID)                  // 1 MB per buffer

typedef __attribute__((ext_vector_type(8))) short  bf16x8;
typedef __attribute__((ext_vector_type(4))) short  s16x4;
typedef __attribute__((ext_vector_type(4))) float  f32x4;
typedef __attribute__((ext_vector_type(4))) int    i32x4;
typedef __attribute__((ext_vector_type(2))) unsigned int u32x2;

__device__ __forceinline__ unsigned short f2bf(float f) {
  unsigned int u = __float_as_uint(f);
  u = (u + 0x7FFFu + ((u >> 16) & 1u)) >> 16;   // RNE
  return (unsigned short)u;
}
__device__ __forceinline__ float b2f(short h) {
  return __uint_as_float(((unsigned int)(unsigned short)h) << 16);
}

// ---- device-coherent (MALL) protocol accesses ----
__device__ __forceinline__ void store_flag(int* p, int v) {
  asm volatile("global_store_dword %0, %1, off sc0 sc1" :: "v"(p), "v"(v) : "memory");
}
__device__ __forceinline__ int load_flag(const int* p) {
  int v;
  asm volatile("global_load_dword %0, %1, off sc0 sc1\n\t"
               "s_waitcnt vmcnt(0)" : "=v"(v) : "v"(p) : "memory");
  return v;
}
__device__ __forceinline__ void store16(void* p, i32x4 v) {
  asm volatile("global_store_dwordx4 %0, %1, off sc0 sc1" :: "v"(p), "v"(v) : "memory");
}
__device__ __forceinline__ void waitcnt0() {
  asm volatile("s_waitcnt vmcnt(0)" ::: "memory");
}
// private per-CU L1 invalidate (sc0 ONLY — not the shared-L2 nuke of R4),
// drained in-asm so the following __syncthreads orders it before A loads.
__device__ __forceinline__ void l1_inv_wait() {
  asm volatile("buffer_inv sc0\n\ts_waitcnt vmcnt(0)" ::: "memory");
}
// raw workgroup barrier: drains LDS ops only
__device__ __forceinline__ void barrier_lgkm() {
  asm volatile("s_waitcnt lgkmcnt(0)\n\ts_barrier" ::: "memory");
}
// head staging: 4x dwordx4 MALL-direct loads (no cache staleness), no wait
__device__ __forceinline__ void issue4(const void* p, i32x4& a, i32x4& b, i32x4& c, i32x4& d) {
  asm volatile(
    "global_load_dwordx4 %0, %4, off sc0 sc1\n\t"
    "global_load_dwordx4 %1, %4, off offset:128 sc0 sc1\n\t"
    "global_load_dwordx4 %2, %4, off offset:256 sc0 sc1\n\t"
    "global_load_dwordx4 %3, %4, off offset:384 sc0 sc1"
    : "=&v"(a), "=&v"(b), "=&v"(c), "=&v"(d)
    : "v"(p) : "memory");
}

__device__ __forceinline__ void wr16(short* p, i32x4 v) {  // 16 B to LDS as 2x b64
  u32x2 lo, hi;
  lo.x = (unsigned)v.x; lo.y = (unsigned)v.y;
  hi.x = (unsigned)v.z; hi.y = (unsigned)v.w;
  *(u32x2*)p = lo;
  *(u32x2*)(p + 4) = hi;
}
__device__ __forceinline__ bf16x8 ld8(const short* p) {    // 8 bf16 from LDS as 2x b64
  union { bf16x8 v8; s16x4 h[2]; } u;
  u.h[0] = *(const s16x4*)p;
  u.h[1] = *(const s16x4*)(p + 4);
  return u.v8;
}
__device__ __forceinline__ bf16x8 ldg8(const short* p) {   // 8 bf16, plain global 16B
  union { bf16x8 v8; i32x4 i4; } u;
  u.i4 = *(const i32x4*)p;
  return u.v8;
}
__device__ __forceinline__ float tanh_fast(float z) {
  float e = __expf(2.f * z);
  return 1.f - 2.f / (e + 1.f);
}

__global__ void __launch_bounds__(256, 1)
rnn_persistent(const float* __restrict__ x, const float* __restrict__ Whx,
               const float* __restrict__ Whh, const float* __restrict__ bh,
               const float* __restrict__ Wph, const float* __restrict__ bp,
               float* __restrict__ out, unsigned short* hbuf, int* flags)
{
  extern __shared__ short smem[];
  short* sW = smem;                 // [JT][WSTR] bf16 W_hh slice, persistent
  short* sS = smem + JT * WSTR;     // head staging [BT][SSTR] (+ hS overlay)

  const int tid  = threadIdx.x;
  const int bg   = blockIdx.x & 15;
  const int jg   = blockIdx.x >> 4;
  const int lane = tid & 63;
  const int wv   = tid >> 6;          // wave = col-tile (16 cols)
  const int l15  = lane & 15;
  const int quad = lane >> 4;

  // ---- stage W_hh[jg*64 .. +64)[0..1024) into LDS as bf16 ----
  {
    const int jr = tid >> 2;
    const int kq = tid & 3;
    const float* src = Whh + (jg * JT + jr) * HID + kq * 256;
    short* dst = sW + jr * WSTR + kq * 256;
#pragma unroll 4
    for (int i = 0; i < 64; ++i) {
      float4 f = *(const float4*)(src + i * 4);
      s16x4 h4;
      h4.x = (short)f2bf(f.x); h4.y = (short)f2bf(f.y);
      h4.z = (short)f2bf(f.z); h4.w = (short)f2bf(f.w);
      *(s16x4*)(dst + i * 4) = h4;
    }
  }

  const int j = jg * JT + wv * 16 + l15;       // this lane's output column
  const float whx = Whx[j];
  const float bhv = bh[j];
  const int grow0 = bg * BT + quad * 4;        // batch row base (acc row group 0)

  // h-store exchange thread mapping: 64 B per thread
  const int sr  = tid >> 3;               // 0..31 row
  const int seg = tid & 7;                // 0..7

  // per-lane MFMA operand bases (constant except hin parity)
  const short* pB = sW + (wv * 16 + l15) * WSTR + quad * 8;   // B: W[j][k-seg]

  int* myflags = flags + bg * 64;         // 16 flags, one 64B line per bg

  for (int t = 0; t < SEQ; ++t) {
    const unsigned short* hin = hbuf + ((t + 1) & 1) * HBUF_HALVES;
    unsigned short*      hout = hbuf + (t & 1) * HBUF_HALVES;

    f32x4 acc0 = {0.f, 0.f, 0.f, 0.f};   // rows quad*4+rg
    f32x4 acc1 = {0.f, 0.f, 0.f, 0.f};   // rows 16+quad*4+rg

    // x for this step — plain loads; compiler inserts waits before use
    float xv0[4], xv1[4];
    {
      const float* xp = x + grow0 * SEQ + t;
#pragma unroll
      for (int rg = 0; rg < 4; ++rg) {
        xv0[rg] = xp[rg * SEQ];
        xv1[rg] = xp[(16 + rg) * SEQ];
      }
    }

    if (t > 0) {
      // acquire: wait for all 16 peers of this batch-group to finish step t-1
      if (tid < GJ) {
        while (load_flag(myflags + tid) < t) {}
      }
      // kill stale L1 lines of hin (read by this CU at t-2); L2 is fresh
      // (producers' sc0 sc1 write-through — R7-verified combination).
      if (tid == 0) l1_inv_wait();
      __syncthreads();

      // A operand direct from global in MFMA fragment layout:
      // lane(l15,quad) row = l15 (+16), k-bytes = quad*16 + ks*64 (contiguous).
      const short* pA0 = (const short*)hin + (bg * BT + l15) * HID + quad * 8;
      const short* pA1 = pA0 + 16 * HID;

#pragma unroll
      for (int ks = 0; ks < 32; ++ks) {
        bf16x8 a0 = ldg8(pA0 + ks * 32);
        bf16x8 a1 = ldg8(pA1 + ks * 32);
        bf16x8 b  = ld8(pB + ks * 32);
        acc0 = __builtin_amdgcn_mfma_f32_16x16x32_bf16(a0, b, acc0, 0, 0, 0);
        acc1 = __builtin_amdgcn_mfma_f32_16x16x32_bf16(a1, b, acc1, 0, 0, 0);
      }
    }

    // ---- epilogue: h = tanh(acc + x*whx + bh) -> hS exchange -> 4KB store ----
    {
      short* hS = sS;   // [BT][HSTR] overlay
#pragma unroll
      for (int rg = 0; rg < 4; ++rg) {
        float z0 = acc0[rg] + xv0[rg] * whx + bhv;
        hS[(quad * 4 + rg) * HSTR + wv * 16 + l15] = (short)f2bf(tanh_fast(z0));
        float z1 = acc1[rg] + xv1[rg] * whx + bhv;
        hS[(16 + quad * 4 + rg) * HSTR + wv * 16 + l15] = (short)f2bf(tanh_fast(z1));
      }
    }
    barrier_lgkm();     // all waves' hS writes visible
    {
      const short* hsrc = sS + sr * HSTR + seg * 8;
      u32x2 lo = *(const u32x2*)(hsrc);
      u32x2 hi = *(const u32x2*)(hsrc + 4);
      i32x4 sv; sv.x = (int)lo.x; sv.y = (int)lo.y; sv.z = (int)hi.x; sv.w = (int)hi.y;
      unsigned short* dst = hout + (bg * BT + sr) * HID + jg * JT + seg * 8;
      store16(dst, sv);
    }
    waitcnt0();          // this thread's coalesced store retired at MALL
    barrier_lgkm();      // all threads retired (and hS reads done) before release
    if (tid == 0) store_flag(myflags + jg, t + 1);
  }

  // ---- output head: out[b, jg*8+cc] = h_last . W_ph[c] + b_p ----
  if (tid < GJ) {
    while (load_flag(myflags + tid) < SEQ) {}
  }
  __syncthreads();

  const unsigned short* hlast = hbuf + ((SEQ - 1) & 1) * HBUF_HALVES;
  const int cc = tid & 7;
  const int cg = jg * 8 + cc;
  const int hr = tid >> 3;
  float acc = 0.f;
  const char* lbase = (const char*)(hlast + (bg * BT + sr) * HID) + seg * 16;
  short* sdst = sS + sr * SSTR + seg * 8;
  for (int c = 0; c < 4; ++c) {
    __syncthreads();
    i32x4 p0, p1, p2, p3;
    issue4(lbase + c * 512, p0, p1, p2, p3);
    waitcnt0();
    wr16(sdst, p0); wr16(sdst + 64, p1); wr16(sdst + 128, p2); wr16(sdst + 192, p3);
    __syncthreads();
    const float* wp = Wph + cg * HID + c * KC;
    const short* hs = sS + hr * SSTR;
#pragma unroll 8
    for (int k4 = 0; k4 < 64; ++k4) {
      float4 w  = *(const float4*)(wp + k4 * 4);
      s16x4 hv  = *(const s16x4*)(hs + k4 * 4);
      acc += b2f(hv.x) * w.x + b2f(hv.y) * w.y + b2f(hv.z) * w.z + b2f(hv.w) * w.w;
    }
  }
  out[(bg * BT + hr) * CLS + cg] = acc + bp[cg];
}

extern "C" void kernel_launch(void* const* d_in, const int* in_sizes, int n_in,
                              void* d_out, int out_size, void* d_ws, size_t ws_size,
                              hipStream_t stream) {
  const float* x   = (const float*)d_in[0];
  const float* Whx = (const float*)d_in[1];
  const float* Whh = (const float*)d_in[2];
  const float* bh  = (const float*)d_in[3];
  const float* Wph = (const float*)d_in[4];
  const float* bp  = (const float*)d_in[5];
  float* out = (float*)d_out;

  unsigned short* hbuf = (unsigned short*)d_ws;
  int* flags = (int*)((char*)d_ws + (size_t)2 * HBUF_HALVES * 2);

  // Zero flags each launch (4 KB, stream-ordered, capture-safe): closes the
  // cross-launch race where stale flags (=SEQ) let consumers run ahead of t=0.
  hipMemsetAsync(flags, 0, GB * 64 * sizeof(int), stream);

  hipFuncSetAttribute(reinterpret_cast<const void*>(rnn_persistent),
                      hipFuncAttributeMaxDynamicSharedMemorySize, SMEM_BYTES);

  rnn_persistent<<<dim3(GB * GJ), dim3(256), SMEM_BYTES, stream>>>(
      x, Whx, Whh, bh, Wph, bp, out, hbuf, flags);
}

// Round 10
// 1153.551 us; speedup vs baseline: 2.0065x; 2.0065x over previous
//
#include <hip/hip_runtime.h>
#include <stdint.h>

// Persistent-kernel RNN: 256 wgs (1/CU), batch split 16 ways, h exchanged via
// MALL (sc0 sc1) + per-group flags (R2 protocol, best verified).
// R12: REGISTER-RESIDENT COMPUTE (R11 concept) with two crash-risk fixes.
//  R11 core-dumped; audit found a rule-#18 violation: the post-burst
//  s_waitcnt vmcnt(0) was a standalone asm ("memory" clobber only) — the
//  register-only MFMA reads of A0..A15 could hoist ABOVE the wait (MFMAs don't
//  touch memory; every passing round tied waited registers with "+v").
//  Fixes vs R11:
//   1. A-wait is register-TIED: one asm binding all 16 i32x4 via "+v",
//      followed by __builtin_amdgcn_sched_barrier(0).
//   2. Gate reverts to R2-verified form: tid<16 flag spin + __syncthreads()
//      (full drain, uniform barrier schedule) — the per-wave gate was the
//      second untested novelty; dropped.
//  Design (unchanged from R11):
//   * B (W_hh): wave wv holds cols jg*64..+64 x k-quarter wv*256..+256 in
//     REGISTERS: barr[4][8] bf16x8 = 128 VGPRs, loaded once. B never in LDS.
//   * A (h): k-split by wave -> disjoint needs; each lane loads its own MFMA
//     A-fragments direct from global (R10-verified addressing) as a 16-deep
//     dwordx4 burst (one RTT — R10's failure was 2-deep pipelining), then 64
//     back-to-back MFMAs.
//   * k-reduction: 32KB LDS f32x4 scratch, lane-contiguous 16B slots (optimal
//     8-phase pattern; R8's stride-32B layout was 2x the bank minimum).
//     Wave wv finishes col-tile wv -> R2 epilogue mapping unchanged.
//  Step cost removed vs R8: ~512 ds_read_b64 + staging writes + ~7 barriers.
// Protocol lessons kept: sc0-only spin hangs (R3); buffer_inv sc1 = L2 nuke
// (R4); data-polling retry storms (R5/R9); scope bits don't change cost (R5==R6).

#define BATCH 512
#define SEQ   256
#define HID   1024
#define CLS   128

#define GB 16          // batch groups
#define GJ 16          // hidden slices
#define BT 32          // batch rows per wg
#define JT 64          // hidden cols per wg
#define KC 256         // head staging chunk (halves)
#define SSTR 260       // head stage row stride (halves)
#define HSTR 68        // h exchange row stride (halves)
#define HS_OFF 16384   // halves: hS overlay at byte 32768 (above 32KB scratch)
#define SMEM_BYTES (32768 + BT * HSTR * 2)   // 37120 B
#define HBUF_HALVES (BATCH * HID)            // 1 MB per buffer

typedef __attribute__((ext_vector_type(8))) short  bf16x8;
typedef __attribute__((ext_vector_type(4))) short  s16x4;
typedef __attribute__((ext_vector_type(4))) float  f32x4;
typedef __attribute__((ext_vector_type(4))) int    i32x4;
typedef __attribute__((ext_vector_type(2))) unsigned int u32x2;

__device__ __forceinline__ unsigned short f2bf(float f) {
  unsigned int u = __float_as_uint(f);
  u = (u + 0x7FFFu + ((u >> 16) & 1u)) >> 16;   // RNE
  return (unsigned short)u;
}
__device__ __forceinline__ float b2f(short h) {
  return __uint_as_float(((unsigned int)(unsigned short)h) << 16);
}

// ---- device-coherent (MALL) protocol accesses ----
__device__ __forceinline__ void store_flag(int* p, int v) {
  asm volatile("global_store_dword %0, %1, off sc0 sc1" :: "v"(p), "v"(v) : "memory");
}
__device__ __forceinline__ int load_flag(const int* p) {
  int v;
  asm volatile("global_load_dword %0, %1, off sc0 sc1\n\t"
               "s_waitcnt vmcnt(0)" : "=v"(v) : "v"(p) : "memory");
  return v;
}
__device__ __forceinline__ void store16(void* p, i32x4 v) {
  asm volatile("global_store_dwordx4 %0, %1, off sc0 sc1" :: "v"(p), "v"(v) : "memory");
}
__device__ __forceinline__ void waitcnt0() {
  asm volatile("s_waitcnt vmcnt(0)" ::: "memory");
}
// raw workgroup barrier: drains LDS ops only
__device__ __forceinline__ void barrier_lgkm() {
  asm volatile("s_waitcnt lgkmcnt(0)\n\ts_barrier" ::: "memory");
}
// head staging: 4x dwordx4, 128B apart (512B chunk)
__device__ __forceinline__ void issue4(const void* p, i32x4& a, i32x4& b, i32x4& c, i32x4& d) {
  asm volatile(
    "global_load_dwordx4 %0, %4, off sc0 sc1\n\t"
    "global_load_dwordx4 %1, %4, off offset:128 sc0 sc1\n\t"
    "global_load_dwordx4 %2, %4, off offset:256 sc0 sc1\n\t"
    "global_load_dwordx4 %3, %4, off offset:384 sc0 sc1"
    : "=&v"(a), "=&v"(b), "=&v"(c), "=&v"(d)
    : "v"(p) : "memory");
}
// A-fragment burst: 4x dwordx4, 64B apart (4 consecutive k-steps of one row)
__device__ __forceinline__ void issue4_64(const void* p, i32x4& a, i32x4& b, i32x4& c, i32x4& d) {
  asm volatile(
    "global_load_dwordx4 %0, %4, off sc0 sc1\n\t"
    "global_load_dwordx4 %1, %4, off offset:64 sc0 sc1\n\t"
    "global_load_dwordx4 %2, %4, off offset:128 sc0 sc1\n\t"
    "global_load_dwordx4 %3, %4, off offset:192 sc0 sc1"
    : "=&v"(a), "=&v"(b), "=&v"(c), "=&v"(d)
    : "v"(p) : "memory");
}

__device__ __forceinline__ void wr16(short* p, i32x4 v) {  // 16 B to LDS as 2x b64
  u32x2 lo, hi;
  lo.x = (unsigned)v.x; lo.y = (unsigned)v.y;
  hi.x = (unsigned)v.z; hi.y = (unsigned)v.w;
  *(u32x2*)p = lo;
  *(u32x2*)(p + 4) = hi;
}
__device__ __forceinline__ float tanh_fast(float z) {
  float e = __expf(2.f * z);
  return 1.f - 2.f / (e + 1.f);
}

#define MFMA(a, b, c) __builtin_amdgcn_mfma_f32_16x16x32_bf16((a), (b), (c), 0, 0, 0)

__global__ void __launch_bounds__(256, 1)
rnn_persistent(const float* __restrict__ x, const float* __restrict__ Whx,
               const float* __restrict__ Whh, const float* __restrict__ bh,
               const float* __restrict__ Wph, const float* __restrict__ bp,
               float* __restrict__ out, unsigned short* hbuf, int* flags)
{
  extern __shared__ short smem[];
  float* scr = (float*)smem;            // 32KB reduction scratch (head reuses)
  short* hS  = smem + HS_OFF;           // [BT][HSTR] exchange overlay

  const int tid  = threadIdx.x;
  const int bg   = blockIdx.x & 15;
  const int jg   = blockIdx.x >> 4;
  const int lane = tid & 63;
  const int wv   = tid >> 6;          // wave = output col-tile AND k-quarter
  const int l15  = lane & 15;
  const int quad = lane >> 4;

  // ---- W_hh into REGISTERS: cols jg*64+ct*16+l15, k = wv*256+ks*32+quad*8 ----
  bf16x8 barr[4][8];
#pragma unroll
  for (int ct = 0; ct < 4; ++ct) {
#pragma unroll
    for (int ks = 0; ks < 8; ++ks) {
      const float* wp = Whh + (jg * JT + ct * 16 + l15) * HID
                            + wv * 256 + ks * 32 + quad * 8;
      float4 fA = *(const float4*)(wp);
      float4 fB = *(const float4*)(wp + 4);
      union { bf16x8 v8; s16x4 h[2]; } u;
      u.h[0].x = (short)f2bf(fA.x); u.h[0].y = (short)f2bf(fA.y);
      u.h[0].z = (short)f2bf(fA.z); u.h[0].w = (short)f2bf(fA.w);
      u.h[1].x = (short)f2bf(fB.x); u.h[1].y = (short)f2bf(fB.y);
      u.h[1].z = (short)f2bf(fB.z); u.h[1].w = (short)f2bf(fB.w);
      barr[ct][ks] = u.v8;
    }
  }

  const int j = jg * JT + wv * 16 + l15;       // this lane's output column
  const float whx = Whx[j];
  const float bhv = bh[j];
  const int grow0 = bg * BT + quad * 4;        // batch row base (row-tile 0)

  // exchange thread mapping: 64 B per thread
  const int sr  = tid >> 3;               // 0..31 row
  const int seg = tid & 7;                // 0..7

  int* myflags = flags + bg * 64;         // 16 flags, one 64B line per bg

  for (int t = 0; t < SEQ; ++t) {
    const unsigned short* hin = hbuf + ((t + 1) & 1) * HBUF_HALVES;
    unsigned short*      hout = hbuf + (t & 1) * HBUF_HALVES;

    f32x4 acc00 = {0,0,0,0}, acc01 = {0,0,0,0}, acc02 = {0,0,0,0}, acc03 = {0,0,0,0};
    f32x4 acc10 = {0,0,0,0}, acc11 = {0,0,0,0}, acc12 = {0,0,0,0}, acc13 = {0,0,0,0};

    // x for this step (plain loads; drained by the gate's full drain)
    float xv0[4], xv1[4];
    {
      const float* xp = x + grow0 * SEQ + t;
#pragma unroll
      for (int rg = 0; rg < 4; ++rg) {
        xv0[rg] = xp[rg * SEQ];
        xv1[rg] = xp[(16 + rg) * SEQ];
      }
    }

    if (t > 0) {
      // acquire (R2-verified): wait for all 16 peers of this batch-group
      if (tid < GJ) {
        while (load_flag(myflags + tid) < t) {}
      }
      __syncthreads();   // full drain: clean vmcnt window for the bursts

      // A fragments direct from global in MFMA layout (R10-verified):
      // row l15 (+16), k-halves = wv*256 + quad*8 + ks*32. 16-deep burst.
      const short* pA0 = (const short*)hin + (bg * BT + l15) * HID
                         + wv * 256 + quad * 8;
      const short* pA1 = pA0 + 16 * HID;
      i32x4 A0, A1, A2, A3, A4, A5, A6, A7, A8, A9, A10, A11, A12, A13, A14, A15;
      issue4_64(pA0,        A0,  A1,  A2,  A3);    // rt0 ks0..3
      issue4_64(pA0 + 128,  A4,  A5,  A6,  A7);    // rt0 ks4..7
      issue4_64(pA1,        A8,  A9,  A10, A11);   // rt1 ks0..3
      issue4_64(pA1 + 128,  A12, A13, A14, A15);   // rt1 ks4..7

      // TIED wait (rule #18): bind every A reg so the MFMAs below cannot be
      // scheduled above the s_waitcnt; sched_barrier pins the boundary.
      asm volatile("s_waitcnt vmcnt(0)"
                   : "+v"(A0), "+v"(A1), "+v"(A2),  "+v"(A3),
                     "+v"(A4), "+v"(A5), "+v"(A6),  "+v"(A7),
                     "+v"(A8), "+v"(A9), "+v"(A10), "+v"(A11),
                     "+v"(A12), "+v"(A13), "+v"(A14), "+v"(A15)
                   :: "memory");
      __builtin_amdgcn_sched_barrier(0);

#define KSTEP(Ar0, Ar1, KS) { \
      bf16x8 _a0 = *(const bf16x8*)&(Ar0); \
      bf16x8 _a1 = *(const bf16x8*)&(Ar1); \
      acc00 = MFMA(_a0, barr[0][KS], acc00); acc10 = MFMA(_a1, barr[0][KS], acc10); \
      acc01 = MFMA(_a0, barr[1][KS], acc01); acc11 = MFMA(_a1, barr[1][KS], acc11); \
      acc02 = MFMA(_a0, barr[2][KS], acc02); acc12 = MFMA(_a1, barr[2][KS], acc12); \
      acc03 = MFMA(_a0, barr[3][KS], acc03); acc13 = MFMA(_a1, barr[3][KS], acc13); }
      KSTEP(A0, A8,  0) KSTEP(A1, A9,  1) KSTEP(A2, A10, 2) KSTEP(A3, A11, 3)
      KSTEP(A4, A12, 4) KSTEP(A5, A13, 5) KSTEP(A6, A14, 6) KSTEP(A7, A15, 7)
#undef KSTEP
    }

    // ---- cross-wave k-reduction: scr slot (group, lane), 16B lane-contiguous ----
    barrier_lgkm();   // prior-step scratch/hS readers done
#pragma unroll
    for (int ct = 0; ct < 4; ++ct) {
      f32x4 w0 = (ct == 0) ? acc00 : (ct == 1) ? acc01 : (ct == 2) ? acc02 : acc03;
      f32x4 w1 = (ct == 0) ? acc10 : (ct == 1) ? acc11 : (ct == 2) ? acc12 : acc13;
      *(f32x4*)(scr + (((ct * 2 + 0) * 4 + wv) * 64 + lane) * 4) = w0;
      *(f32x4*)(scr + (((ct * 2 + 1) * 4 + wv) * 64 + lane) * 4) = w1;
    }
    barrier_lgkm();
    {
      f32x4 f0 = {0,0,0,0}, f1 = {0,0,0,0};
#pragma unroll
      for (int w = 0; w < 4; ++w) {
        f0 += *(const f32x4*)(scr + (((wv * 2 + 0) * 4 + w) * 64 + lane) * 4);
        f1 += *(const f32x4*)(scr + (((wv * 2 + 1) * 4 + w) * 64 + lane) * 4);
      }
      // h = tanh(acc + x*whx + bh) -> hS (wave wv owns col-tile wv)
#pragma unroll
      for (int rg = 0; rg < 4; ++rg) {
        float z0 = f0[rg] + xv0[rg] * whx + bhv;
        hS[(quad * 4 + rg) * HSTR + wv * 16 + l15] = (short)f2bf(tanh_fast(z0));
        float z1 = f1[rg] + xv1[rg] * whx + bhv;
        hS[(16 + quad * 4 + rg) * HSTR + wv * 16 + l15] = (short)f2bf(tanh_fast(z1));
      }
    }
    barrier_lgkm();   // hS complete
    {
      const short* hsrc = hS + sr * HSTR + seg * 8;
      u32x2 lo = *(const u32x2*)(hsrc);
      u32x2 hi = *(const u32x2*)(hsrc + 4);
      i32x4 sv; sv.x = (int)lo.x; sv.y = (int)lo.y; sv.z = (int)hi.x; sv.w = (int)hi.y;
      unsigned short* dst = hout + (bg * BT + sr) * HID + jg * JT + seg * 8;
      store16(dst, sv);
    }
    waitcnt0();          // this thread's 4KB-coalesced store retired at MALL
    barrier_lgkm();      // all threads retired before the flag release
    if (tid == 0) store_flag(myflags + jg, t + 1);
  }

  // ---- output head: out[b, jg*8+cc] = h_last . W_ph[c] + b_p ----
  if (tid < GJ) {
    while (load_flag(myflags + tid) < SEQ) {}
  }
  __syncthreads();

  const unsigned short* hlast = hbuf + ((SEQ - 1) & 1) * HBUF_HALVES;
  short* sS = smem;                       // head staging overlays scratch
  const int cc = tid & 7;
  const int cg = jg * 8 + cc;
  const int hr = tid >> 3;
  float acc = 0.f;
  const char* lbase = (const char*)(hlast + (bg * BT + sr) * HID) + seg * 16;
  short* sdst = sS + sr * SSTR + seg * 8;
  for (int c = 0; c < 4; ++c) {
    __syncthreads();
    i32x4 p0, p1, p2, p3;
    issue4(lbase + c * 512, p0, p1, p2, p3);
    waitcnt0();
    wr16(sdst, p0); wr16(sdst + 64, p1); wr16(sdst + 128, p2); wr16(sdst + 192, p3);
    __syncthreads();
    const float* wp = Wph + cg * HID + c * KC;
    const short* hs = sS + hr * SSTR;
#pragma unroll 8
    for (int k4 = 0; k4 < 64; ++k4) {
      float4 w  = *(const float4*)(wp + k4 * 4);
      s16x4 hv  = *(const s16x4*)(hs + k4 * 4);
      acc += b2f(hv.x) * w.x + b2f(hv.y) * w.y + b2f(hv.z) * w.z + b2f(hv.w) * w.w;
    }
  }
  out[(bg * BT + hr) * CLS + cg] = acc + bp[cg];
}

extern "C" void kernel_launch(void* const* d_in, const int* in_sizes, int n_in,
                              void* d_out, int out_size, void* d_ws, size_t ws_size,
                              hipStream_t stream) {
  const float* x   = (const float*)d_in[0];
  const float* Whx = (const float*)d_in[1];
  const float* Whh = (const float*)d_in[2];
  const float* bh  = (const float*)d_in[3];
  const float* Wph = (const float*)d_in[4];
  const float* bp  = (const float*)d_in[5];
  float* out = (float*)d_out;

  unsigned short* hbuf = (unsigned short*)d_ws;
  int* flags = (int*)((char*)d_ws + (size_t)2 * HBUF_HALVES * 2);

  // Zero flags each launch (stream-ordered, capture-safe): closes the
  // cross-launch race where stale flags (=SEQ) would let consumers run ahead.
  hipMemsetAsync(flags, 0, GB * 64 * sizeof(int), stream);

  hipFuncSetAttribute(reinterpret_cast<const void*>(rnn_persistent),
                      hipFuncAttributeMaxDynamicSharedMemorySize, SMEM_BYTES);

  rnn_persistent<<<dim3(GB * GJ), dim3(256), SMEM_BYTES, stream>>>(
      x, Whx, Whh, bh, Wph, bp, out, hbuf, flags);
}